// Round 6
// baseline (427.930 us; speedup 1.0000x reference)
//
#include <hip/hip_runtime.h>

typedef unsigned short u16;
typedef u16   u16x4  __attribute__((ext_vector_type(4)));
typedef u16   u16x8  __attribute__((ext_vector_type(8)));
typedef short short8 __attribute__((ext_vector_type(8)));
typedef float floatx4 __attribute__((ext_vector_type(4)));
typedef float f4     __attribute__((ext_vector_type(4)));

#define BB 8
#define NN 4096
#define CC 384

__device__ __forceinline__ u16 f2bf(float f){
  unsigned u = __float_as_uint(f);
  u += 0x7FFFu + ((u >> 16) & 1u);   // round-to-nearest-even
  return (u16)(u >> 16);
}

// ---------------- Kernel 0: WT[col][k] = bf16(wqkv[k][col])  (1152 x 384, one-time transpose) ----
__global__ __launch_bounds__(256) void k_prep(const float* __restrict__ wqkv, u16* __restrict__ WT)
{
  const int cg = blockIdx.x % 18;        // 18 col-groups of 64
  const int kg = blockIdx.x / 18;        // 6 k-groups of 64
  const int c0 = cg << 6, k0 = kg << 6;
  const int tid = threadIdx.x;
  __shared__ u16 t[64][72];
#pragma unroll
  for (int i = 0; i < 4; i++) {
    int idx = tid + (i << 8);            // 0..1023
    int r = idx >> 4, c4 = (idx & 15) << 2;
    f4 v = *(const f4*)(wqkv + (size_t)(k0 + r) * 1152 + c0 + c4);
#pragma unroll
    for (int j = 0; j < 4; j++) t[c4 + j][r] = f2bf(v[j]);
  }
  __syncthreads();
#pragma unroll
  for (int i = 0; i < 2; i++) {
    int idx = tid + (i << 8);            // 0..511
    int c = idx >> 3, j = (idx & 7) << 3;
    *(u16x8*)(WT + (size_t)(c0 + c) * 384 + k0 + j) = *(const u16x8*)&t[c][j];
  }
}

// ---------------- Kernel 1: depthwise conv 3x3 + LN + GELU(erf) + residual -> xa16 (bf16) -------
__global__ __launch_bounds__(384) void k_conv_ln_gelu(
    const float* __restrict__ x, const float* __restrict__ w_sr, const float* __restrict__ b_sr,
    const float* __restrict__ ln_g, const float* __restrict__ ln_b, u16* __restrict__ xa16)
{
  const int blk = blockIdx.x;          // b*512 + hh*8 + wg
  const int b = blk >> 9;
  const int hh = (blk >> 3) & 63;
  const int ww0 = (blk & 7) << 3;      // pixels ww0..ww0+7
  const int c = threadIdx.x;

  float wgt[9];
#pragma unroll
  for (int i = 0; i < 9; i++) wgt[i] = w_sr[c * 9 + i];
  const float lg = ln_g[c], lb = ln_b[c];
  const float bias = b_sr[c];

  float rowv[3][10];
#pragma unroll
  for (int r = 0; r < 3; r++) {
    int y = hh + r - 1;
    bool yok = (unsigned)y < 64u;
#pragma unroll
    for (int j = 0; j < 10; j++) {
      int xx = ww0 + j - 1;
      bool ok = yok && ((unsigned)xx < 64u);
      rowv[r][j] = ok ? x[((size_t)((b << 12) + (y << 6) + xx)) * CC + c] : 0.f;
    }
  }

  float acc[8];
#pragma unroll
  for (int p = 0; p < 8; p++) {
    float a = bias;
#pragma unroll
    for (int r = 0; r < 3; r++)
#pragma unroll
      for (int j = 0; j < 3; j++)
        a += rowv[r][p + j] * wgt[r * 3 + j];
    acc[p] = a;
  }

  __shared__ float ls1[6][8], ls2[6][8], mb[2][8];
  const int wid = threadIdx.x >> 6, lane = threadIdx.x & 63;
#pragma unroll
  for (int p = 0; p < 8; p++) {
    float s1 = acc[p], s2 = acc[p] * acc[p];
#pragma unroll
    for (int o = 32; o > 0; o >>= 1) { s1 += __shfl_down(s1, o); s2 += __shfl_down(s2, o); }
    if (lane == 0) { ls1[wid][p] = s1; ls2[wid][p] = s2; }
  }
  __syncthreads();
  if (threadIdx.x < 8) {
    int p = threadIdx.x;
    float a = 0.f, q = 0.f;
#pragma unroll
    for (int i = 0; i < 6; i++) { a += ls1[i][p]; q += ls2[i][p]; }
    float mean = a * (1.0f / CC);
    float var  = q * (1.0f / CC) - mean * mean;
    mb[0][p] = mean; mb[1][p] = rsqrtf(var + 1e-5f);
  }
  __syncthreads();
#pragma unroll
  for (int p = 0; p < 8; p++) {
    float xn = (acc[p] - mb[0][p]) * mb[1][p] * lg + lb;
    float g  = 0.5f * xn * (1.0f + erff(xn * 0.70710678118654752f));
    size_t pix = (size_t)(b << 12) + (hh << 6) + ww0 + p;
    xa16[pix * CC + c] = f2bf(rowv[1][p + 1] + g);   // center tap doubles as residual
  }
}

// ---------------- Kernel 2: fused qkv GEMM (3 col-groups: k, v, q) --------------------------------
// qsumk-proven structure. k-group: per-head register softmax -> K16T (transposed, n-contiguous).
// v-group: -> V16T. q-group (last): exp -> P16 in-place over xa16 + column-sum atomics into S.
__global__ __launch_bounds__(256) void k_qkv(
    const u16* __restrict__ xa16, const u16* __restrict__ WT, float* __restrict__ S,
    u16* __restrict__ K16T, u16* __restrict__ V16T, u16* __restrict__ P16)
{
  const int bm = blockIdx.x;           // 512 row-tiles of 64
  const int b = bm >> 6;
  const int tid = threadIdx.x;
  const int wv = tid >> 6, lane = tid & 63, l15 = lane & 15, quad = lane >> 4;
  __shared__ __attribute__((aligned(16))) u16 lB[384][40];

  const size_t arow = (size_t)((bm << 6) + (wv << 4) + l15) * 384;
  const int nloc = ((bm & 63) << 6) + (wv << 4) + (quad << 2);  // n-index of this thread's 4 rows

  floatx4 acc[24];
  const floatx4 z = {0.f, 0.f, 0.f, 0.f};

#pragma unroll
  for (int gi = 0; gi < 3; gi++) {
    const int g = (gi == 0) ? 1 : (gi == 1) ? 2 : 0;   // process k, then v, then q (q last!)
#pragma unroll
    for (int i = 0; i < 24; i++) acc[i] = z;

    for (int k0 = 0; k0 < 384; k0 += 32) {
      __syncthreads();
#pragma unroll
      for (int i = 0; i < 6; i++) {
        int idx = tid + (i << 8);            // 0..1535 chunks of 8
        int cl = idx >> 2, ko = (idx & 3) << 3;
        *(u16x8*)&lB[cl][ko] = *(const u16x8*)(WT + (size_t)(g * 384 + cl) * 384 + k0 + ko);
      }
      __syncthreads();
      short8 af = *(const short8*)(xa16 + arow + k0 + (quad << 3));
#pragma unroll
      for (int ct = 0; ct < 24; ct++) {
        short8 bf = *(const short8*)&lB[(ct << 4) + l15][quad << 3];
        acc[ct] = __builtin_amdgcn_mfma_f32_16x16x32_bf16(af, bf, acc[ct], 0, 0, 0);
      }
    }

    if (g == 1) {
      // per-row, per-head softmax over 48 dims (3 regs x 16 lanes, shfl_xor within quad-group)
#pragma unroll
      for (int rr = 0; rr < 4; rr++) {
#pragma unroll
        for (int h = 0; h < 8; h++) {
          float x0 = acc[3*h+0][rr], x1 = acc[3*h+1][rr], x2 = acc[3*h+2][rr];
          float m = fmaxf(fmaxf(x0, x1), x2);
#pragma unroll
          for (int o = 8; o >= 1; o >>= 1) m = fmaxf(m, __shfl_xor(m, o));
          float e0 = expf(x0 - m), e1 = expf(x1 - m), e2 = expf(x2 - m);
          float s = e0 + e1 + e2;
#pragma unroll
          for (int o = 8; o >= 1; o >>= 1) s += __shfl_xor(s, o);
          float inv = 1.0f / s;
          acc[3*h+0][rr] = e0 * inv; acc[3*h+1][rr] = e1 * inv; acc[3*h+2][rr] = e2 * inv;
        }
      }
#pragma unroll
      for (int t = 0; t < 24; t++) {
        int col = (t << 4) + l15;            // hd index 0..383
        u16x4 v4 = { f2bf(acc[t][0]), f2bf(acc[t][1]), f2bf(acc[t][2]), f2bf(acc[t][3]) };
        *(u16x4*)(K16T + ((size_t)b * 384 + col) * 4096 + nloc) = v4;
      }
    } else if (g == 2) {
#pragma unroll
      for (int t = 0; t < 24; t++) {
        int col = (t << 4) + l15;
        u16x4 v4 = { f2bf(acc[t][0]), f2bf(acc[t][1]), f2bf(acc[t][2]), f2bf(acc[t][3]) };
        *(u16x4*)(V16T + ((size_t)b * 384 + col) * 4096 + nloc) = v4;
      }
    } else {
#pragma unroll
      for (int t = 0; t < 24; t++) {
        int col = (t << 4) + l15;
        float e0 = expf(acc[t][0]), e1 = expf(acc[t][1]), e2 = expf(acc[t][2]), e3 = expf(acc[t][3]);
        int rowb = (bm << 6) + (wv << 4) + (quad << 2);
        P16[(size_t)(rowb + 0) * 384 + col] = f2bf(e0);
        P16[(size_t)(rowb + 1) * 384 + col] = f2bf(e1);
        P16[(size_t)(rowb + 2) * 384 + col] = f2bf(e2);
        P16[(size_t)(rowb + 3) * 384 + col] = f2bf(e3);
        float s = e0 + e1 + e2 + e3;
        s += __shfl_down(s, 32);
        s += __shfl_down(s, 16);
        if (lane < 16) atomicAdd(&S[b * 384 + (t << 4) + lane], s);
      }
    }
  }
}

// ---------------- Kernel 3: ctx[bh,48,48] += ksm^T @ v over 256-row n-chunks (MFMA) -------------
// grid (64 bh, 16 chunks), block 256. K16T/V16T rows are n-contiguous -> coalesced vector staging.
__global__ __launch_bounds__(256) void k_ctx(
    const u16* __restrict__ K16T, const u16* __restrict__ V16T, float* __restrict__ ctx)
{
  const int bh = blockIdx.x;           // 64
  const int b = bh >> 3, h = bh & 7;
  const int n0 = blockIdx.y << 8;      // chunk of 256 n
  const int tid = threadIdx.x;
  const int wv = tid >> 6, lane = tid & 63, l15 = lane & 15, quad = lane >> 4;

  __shared__ __attribute__((aligned(16))) char smem[50688];
  u16 (*lkT)[264] = (u16(*)[264])smem;             // 48 x 264 (ksm^T: [d][n])
  u16 (*lvT)[264] = (u16(*)[264])(smem + 25344);   // 48 x 264 (v^T:   [e][n])
  float (*pctx)[2304] = (float(*)[2304])smem;      // 4 x 2304 (overlaps, used after barrier)

#pragma unroll
  for (int i = 0; i < 6; i++) {
    int idx = tid + (i << 8);          // 0..1535
    int d = idx >> 5, c8 = (idx & 31) << 3;
    *(u16x8*)&lkT[d][c8] = *(const u16x8*)(K16T + ((size_t)b * 384 + h * 48 + d) * 4096 + n0 + c8);
    *(u16x8*)&lvT[d][c8] = *(const u16x8*)(V16T + ((size_t)b * 384 + h * 48 + d) * 4096 + n0 + c8);
  }
  __syncthreads();

  floatx4 c2[9];
  const floatx4 z = {0.f, 0.f, 0.f, 0.f};
#pragma unroll
  for (int i = 0; i < 9; i++) c2[i] = z;
#pragma unroll
  for (int kk2 = 0; kk2 < 2; kk2++) {
    int rb = (wv << 6) + (kk2 << 5) + (quad << 3);
    short8 ak[3], av[3];
#pragma unroll
    for (int t = 0; t < 3; t++) {
      ak[t] = *(const short8*)&lkT[(t << 4) + l15][rb];
      av[t] = *(const short8*)&lvT[(t << 4) + l15][rb];
    }
#pragma unroll
    for (int dt = 0; dt < 3; dt++)
#pragma unroll
      for (int et = 0; et < 3; et++)
        c2[dt * 3 + et] = __builtin_amdgcn_mfma_f32_16x16x32_bf16(ak[dt], av[et], c2[dt * 3 + et], 0, 0, 0);
  }
  __syncthreads();   // done reading lkT/lvT; smem reused as pctx

#pragma unroll
  for (int dt = 0; dt < 3; dt++)
#pragma unroll
    for (int et = 0; et < 3; et++)
#pragma unroll
      for (int rr = 0; rr < 4; rr++) {
        int d = (dt << 4) + (quad << 2) + rr;
        int e = (et << 4) + l15;
        pctx[wv][d * 48 + e] = c2[dt * 3 + et][rr];
      }
  __syncthreads();
#pragma unroll
  for (int i = 0; i < 9; i++) {
    int cell = tid + (i << 8);
    float s = pctx[0][cell] + pctx[1][cell] + pctx[2][cell] + pctx[3][cell];
    atomicAdd(&ctx[(size_t)bh * 2304 + cell], s);
  }
}

// ---------------- Kernel 4: W2T[b, c, h*48+d] = sum_e (ctx[bh,d,e]/S[..]) * wp[h*48+e, c] -------
__global__ __launch_bounds__(256) void k_w2(
    const float* __restrict__ ctx, const float* __restrict__ S,
    const float* __restrict__ wp, u16* __restrict__ W2T)
{
  const int bh = blockIdx.x;   // 64
  const int b = bh >> 3, h = bh & 7;
  const int c0 = blockIdx.y << 7;
  const int tid = threadIdx.x;
  __shared__ float rs[48];
  __shared__ float c2[48][48];
  __shared__ float lwp[48][128];
  __shared__ u16 tr[128][48];
  if (tid < 48) rs[tid] = 1.0f / S[b * 384 + h * 48 + tid];
  __syncthreads();
#pragma unroll
  for (int i = 0; i < 9; i++) {
    int cell = tid + (i << 8);
    int d = cell / 48, e = cell - d * 48;
    c2[d][e] = ctx[(size_t)bh * 2304 + cell] * rs[d];
  }
#pragma unroll
  for (int i = 0; i < 24; i++) {
    int idx = tid + (i << 8);            // 0..6143
    int e = idx >> 7, c = idx & 127;
    lwp[e][c] = wp[(size_t)(h * 48 + e) * 384 + c0 + c];
  }
  __syncthreads();
  const int c = tid & 127;
  const int dbase = tid >> 7;            // 0 or 1
#pragma unroll
  for (int it = 0; it < 24; it++) {
    int d = (it << 1) + dbase;
    float s = 0.f;
#pragma unroll
    for (int e = 0; e < 48; e++) s += c2[d][e] * lwp[e][c];
    tr[c][d] = f2bf(s);
  }
  __syncthreads();
  const int cc = tid >> 1, half = tid & 1;
#pragma unroll
  for (int i = 0; i < 3; i++) {
    u16x8 v = *(const u16x8*)&tr[cc][half * 24 + (i << 3)];
    *(u16x8*)(W2T + ((size_t)b * 384 + c0 + cc) * 384 + h * 48 + half * 24 + (i << 3)) = v;
  }
}

// ---------------- Kernel 5: out = P_tile @ W2_b + bias + x  (direct-global A from P16) ----------
__global__ __launch_bounds__(256) void k_qproj(
    const u16* __restrict__ P16, const u16* __restrict__ W2T,
    const float* __restrict__ bias, const float* __restrict__ x, float* __restrict__ out)
{
  const int bm = blockIdx.x;           // 512 row-tiles of 64
  const int b = bm >> 6;
  const int tid = threadIdx.x;
  const int wv = tid >> 6, lane = tid & 63, l15 = lane & 15, quad = lane >> 4;
  __shared__ __attribute__((aligned(16))) u16 lB[384][40];

  floatx4 acc[24];
  const floatx4 z = {0.f, 0.f, 0.f, 0.f};
#pragma unroll
  for (int i = 0; i < 24; i++) acc[i] = z;

  const size_t arow = (size_t)((bm << 6) + (wv << 4) + l15) * 384;

  for (int k0 = 0; k0 < 384; k0 += 32) {
    __syncthreads();
#pragma unroll
    for (int i = 0; i < 6; i++) {
      int idx = tid + (i << 8);
      int cl = idx >> 2, ko = (idx & 3) << 3;
      *(u16x8*)&lB[cl][ko] = *(const u16x8*)(W2T + ((size_t)b * 384 + cl) * 384 + k0 + ko);
    }
    __syncthreads();
    short8 af = *(const short8*)(P16 + arow + k0 + (quad << 3));
#pragma unroll
    for (int ct = 0; ct < 24; ct++) {
      short8 bf = *(const short8*)&lB[(ct << 4) + l15][quad << 3];
      acc[ct] = __builtin_amdgcn_mfma_f32_16x16x32_bf16(af, bf, acc[ct], 0, 0, 0);
    }
  }
  // epilogue: + bias + x, write out
#pragma unroll
  for (int t = 0; t < 24; t++) {
    int col = (t << 4) + l15;
#pragma unroll
    for (int rr = 0; rr < 4; rr++) {
      int row = (bm << 6) + (wv << 4) + (quad << 2) + rr;
      float v = acc[t][rr] + bias[col] + x[(size_t)row * 384 + col];
      out[(size_t)row * 384 + col] = v;
    }
  }
}

extern "C" void kernel_launch(void* const* d_in, const int* in_sizes, int n_in,
                              void* d_out, int out_size, void* d_ws, size_t ws_size,
                              hipStream_t stream)
{
  const float* x      = (const float*)d_in[0];
  const float* w_sr   = (const float*)d_in[1];
  const float* b_sr   = (const float*)d_in[2];
  const float* ln_g   = (const float*)d_in[3];
  const float* ln_b   = (const float*)d_in[4];
  const float* w_qkv  = (const float*)d_in[5];
  const float* w_proj = (const float*)d_in[6];
  const float* b_proj = (const float*)d_in[7];
  float* out = (float*)d_out;

  // ws layout — total 29,011,968 bytes (~29 MB):
  //   [0,        12288)     S    [8][384] f32
  //   [12288,    602112)    ctx  [64][48][48] f32
  //   [602112,   1486848)   WT   [1152][384] bf16
  //   [1486848,  3846144)   W2T  [8][384][384] bf16
  //   [3846144,  29011968)  xa16 [32768][384] bf16  (overwritten in-place by P16=bf16(exp(q)))
  // d_out (50.3 MB) doubles as scratch for K16T+V16T (2 x 25.17 MB) until k_qproj writes it.
  float* S   = (float*)d_ws;
  float* ctx = (float*)((char*)d_ws + 12288);
  u16*   WT  = (u16*)((char*)d_ws + 602112);
  u16*   W2T = (u16*)((char*)d_ws + 1486848);
  u16*   xa16= (u16*)((char*)d_ws + 3846144);
  u16*   P16 = xa16;                     // in-place: k_qkv overwrites its own rows after last read
  u16*   K16T= (u16*)d_out;              // [8][384][4096] bf16
  u16*   V16T= (u16*)d_out + (size_t)8 * 384 * 4096;

  hipMemsetAsync(d_ws, 0, 602112, stream);   // zero S + ctx

  k_prep<<<108, 256, 0, stream>>>(w_qkv, WT);
  k_conv_ln_gelu<<<BB * 512, 384, 0, stream>>>(x, w_sr, b_sr, ln_g, ln_b, xa16);
  k_qkv<<<512, 256, 0, stream>>>(xa16, WT, S, K16T, V16T, P16);
  k_ctx<<<dim3(64, 16), 256, 0, stream>>>(K16T, V16T, ctx);
  k_w2<<<dim3(64, 3), 256, 0, stream>>>(ctx, S, w_proj, W2T);
  k_qproj<<<512, 256, 0, stream>>>(P16, W2T, b_proj, x, out);
}

// Round 7
// 315.390 us; speedup vs baseline: 1.3568x; 1.3568x over previous
//
#include <hip/hip_runtime.h>

typedef unsigned short u16;
typedef u16   u16x4  __attribute__((ext_vector_type(4)));
typedef u16   u16x8  __attribute__((ext_vector_type(8)));
typedef short short8 __attribute__((ext_vector_type(8)));
typedef float floatx4 __attribute__((ext_vector_type(4)));
typedef float f4     __attribute__((ext_vector_type(4)));

#define BB 8
#define NN 4096
#define CC 384

__device__ __forceinline__ u16 f2bf(float f){
  unsigned u = __float_as_uint(f);
  u += 0x7FFFu + ((u >> 16) & 1u);   // round-to-nearest-even
  return (u16)(u >> 16);
}

// ---------------- Kernel 0: WT[col][k] = bf16(wqkv[k][col])  (1152 x 384, one-time transpose) ----
__global__ __launch_bounds__(256) void k_prep(const float* __restrict__ wqkv, u16* __restrict__ WT)
{
  const int cg = blockIdx.x % 18;        // 18 col-groups of 64
  const int kg = blockIdx.x / 18;        // 6 k-groups of 64
  const int c0 = cg << 6, k0 = kg << 6;
  const int tid = threadIdx.x;
  __shared__ u16 t[64][72];
#pragma unroll
  for (int i = 0; i < 4; i++) {
    int idx = tid + (i << 8);            // 0..1023
    int r = idx >> 4, c4 = (idx & 15) << 2;
    f4 v = *(const f4*)(wqkv + (size_t)(k0 + r) * 1152 + c0 + c4);
#pragma unroll
    for (int j = 0; j < 4; j++) t[c4 + j][r] = f2bf(v[j]);
  }
  __syncthreads();
#pragma unroll
  for (int i = 0; i < 2; i++) {
    int idx = tid + (i << 8);            // 0..511
    int c = idx >> 3, j = (idx & 7) << 3;
    *(u16x8*)(WT + (size_t)(c0 + c) * 384 + k0 + j) = *(const u16x8*)&t[c][j];
  }
}

// ---------------- Kernel 1: depthwise conv 3x3 + LN + GELU(erf) + residual -> xa16 (bf16) -------
__global__ __launch_bounds__(384) void k_conv_ln_gelu(
    const float* __restrict__ x, const float* __restrict__ w_sr, const float* __restrict__ b_sr,
    const float* __restrict__ ln_g, const float* __restrict__ ln_b, u16* __restrict__ xa16)
{
  const int blk = blockIdx.x;          // b*512 + hh*8 + wg
  const int b = blk >> 9;
  const int hh = (blk >> 3) & 63;
  const int ww0 = (blk & 7) << 3;      // pixels ww0..ww0+7
  const int c = threadIdx.x;

  float wgt[9];
#pragma unroll
  for (int i = 0; i < 9; i++) wgt[i] = w_sr[c * 9 + i];
  const float lg = ln_g[c], lb = ln_b[c];
  const float bias = b_sr[c];

  float rowv[3][10];
#pragma unroll
  for (int r = 0; r < 3; r++) {
    int y = hh + r - 1;
    bool yok = (unsigned)y < 64u;
#pragma unroll
    for (int j = 0; j < 10; j++) {
      int xx = ww0 + j - 1;
      bool ok = yok && ((unsigned)xx < 64u);
      rowv[r][j] = ok ? x[((size_t)((b << 12) + (y << 6) + xx)) * CC + c] : 0.f;
    }
  }

  float acc[8];
#pragma unroll
  for (int p = 0; p < 8; p++) {
    float a = bias;
#pragma unroll
    for (int r = 0; r < 3; r++)
#pragma unroll
      for (int j = 0; j < 3; j++)
        a += rowv[r][p + j] * wgt[r * 3 + j];
    acc[p] = a;
  }

  __shared__ float ls1[6][8], ls2[6][8], mb[2][8];
  const int wid = threadIdx.x >> 6, lane = threadIdx.x & 63;
#pragma unroll
  for (int p = 0; p < 8; p++) {
    float s1 = acc[p], s2 = acc[p] * acc[p];
#pragma unroll
    for (int o = 32; o > 0; o >>= 1) { s1 += __shfl_down(s1, o); s2 += __shfl_down(s2, o); }
    if (lane == 0) { ls1[wid][p] = s1; ls2[wid][p] = s2; }
  }
  __syncthreads();
  if (threadIdx.x < 8) {
    int p = threadIdx.x;
    float a = 0.f, q = 0.f;
#pragma unroll
    for (int i = 0; i < 6; i++) { a += ls1[i][p]; q += ls2[i][p]; }
    float mean = a * (1.0f / CC);
    float var  = q * (1.0f / CC) - mean * mean;
    mb[0][p] = mean; mb[1][p] = rsqrtf(var + 1e-5f);
  }
  __syncthreads();
#pragma unroll
  for (int p = 0; p < 8; p++) {
    float xn = (acc[p] - mb[0][p]) * mb[1][p] * lg + lb;
    float g  = 0.5f * xn * (1.0f + erff(xn * 0.70710678118654752f));
    size_t pix = (size_t)(b << 12) + (hh << 6) + ww0 + p;
    xa16[pix * CC + c] = f2bf(rowv[1][p + 1] + g);   // center tap doubles as residual
  }
}

// ---------------- Kernel 2: k|v GEMM, 128x192 tile, per-wave 64x96 (2 whole heads) --------------
// grid (256 rowtiles, 4: g{k,v} x 2 coltiles), block 256 (4 waves, 2r x 2c).
// k-group: per-head register softmax. Stores transposed to K16T/V16T [b][384][4096].
__global__ __launch_bounds__(256) void k_kv(
    const u16* __restrict__ xa16, const u16* __restrict__ WT,
    u16* __restrict__ K16T, u16* __restrict__ V16T)
{
  const int rt = blockIdx.x;            // 256 rowtiles of 128
  const int gy = blockIdx.y;            // 0..3
  const int g = gy >> 1, ct0 = gy & 1;  // g: 0=k, 1=v
  const int b = rt >> 5;
  const int n0 = rt << 7;
  const int cbase = (g ? 768 : 384) + ct0 * 192;
  const int tid = threadIdx.x;
  const int wv = tid >> 6, lane = tid & 63, l15 = lane & 15, quad = lane >> 4;
  const int wr = wv >> 1, wc = wv & 1;

  __shared__ __attribute__((aligned(16))) u16 lA[128][40];
  __shared__ __attribute__((aligned(16))) u16 lB[192][40];

  floatx4 acc[24];
  const floatx4 z = {0.f, 0.f, 0.f, 0.f};
#pragma unroll
  for (int i = 0; i < 24; i++) acc[i] = z;

  for (int k0 = 0; k0 < 384; k0 += 32) {
    __syncthreads();
#pragma unroll
    for (int i = 0; i < 2; i++) {                       // A: 128 rows x 32 k
      int idx = tid + (i << 8);                         // 0..511
      int r = idx >> 2, c8 = (idx & 3) << 3;
      *(u16x8*)&lA[r][c8] = *(const u16x8*)(xa16 + (size_t)(n0 + r) * 384 + k0 + c8);
    }
#pragma unroll
    for (int i = 0; i < 3; i++) {                       // B: 192 cols x 32 k
      int idx = tid + (i << 8);                         // 0..767
      int cl = idx >> 2, ko = (idx & 3) << 3;
      *(u16x8*)&lB[cl][ko] = *(const u16x8*)(WT + (size_t)(cbase + cl) * 384 + k0 + ko);
    }
    __syncthreads();
    short8 af[4], bf[6];
#pragma unroll
    for (int mi = 0; mi < 4; mi++)
      af[mi] = *(const short8*)&lA[(wr << 6) + (mi << 4) + l15][quad << 3];
#pragma unroll
    for (int ni = 0; ni < 6; ni++)
      bf[ni] = *(const short8*)&lB[(wc * 96) + (ni << 4) + l15][quad << 3];
#pragma unroll
    for (int mi = 0; mi < 4; mi++)
#pragma unroll
      for (int ni = 0; ni < 6; ni++)
        acc[mi * 6 + ni] = __builtin_amdgcn_mfma_f32_16x16x32_bf16(af[mi], bf[ni], acc[mi * 6 + ni], 0, 0, 0);
  }

  if (g == 0) {
    // per-head softmax: head block hb covers ni = 3*hb .. 3*hb+2 (48 cols across 16 l15 lanes)
#pragma unroll
    for (int mi = 0; mi < 4; mi++)
#pragma unroll
      for (int hb = 0; hb < 2; hb++)
#pragma unroll
        for (int rr = 0; rr < 4; rr++) {
          float x0 = acc[mi * 6 + 3 * hb + 0][rr];
          float x1 = acc[mi * 6 + 3 * hb + 1][rr];
          float x2 = acc[mi * 6 + 3 * hb + 2][rr];
          float m = fmaxf(fmaxf(x0, x1), x2);
#pragma unroll
          for (int o = 8; o >= 1; o >>= 1) m = fmaxf(m, __shfl_xor(m, o));
          float e0 = expf(x0 - m), e1 = expf(x1 - m), e2 = expf(x2 - m);
          float s = e0 + e1 + e2;
#pragma unroll
          for (int o = 8; o >= 1; o >>= 1) s += __shfl_xor(s, o);
          float inv = 1.0f / s;
          acc[mi * 6 + 3 * hb + 0][rr] = e0 * inv;
          acc[mi * 6 + 3 * hb + 1][rr] = e1 * inv;
          acc[mi * 6 + 3 * hb + 2][rr] = e2 * inv;
        }
  }

  u16* dst = (g == 0) ? K16T : V16T;
  const int nloc = ((rt & 31) << 7) + (wr << 6) + (quad << 2);
#pragma unroll
  for (int mi = 0; mi < 4; mi++)
#pragma unroll
    for (int ni = 0; ni < 6; ni++) {
      int hd = ct0 * 192 + wc * 96 + (ni << 4) + l15;   // 0..383
      u16x4 v4 = { f2bf(acc[mi * 6 + ni][0]), f2bf(acc[mi * 6 + ni][1]),
                   f2bf(acc[mi * 6 + ni][2]), f2bf(acc[mi * 6 + ni][3]) };
      *(u16x4*)(dst + ((size_t)b * 384 + hd) * 4096 + nloc + (mi << 4)) = v4;
    }
}

// ---------------- Kernel 3: q GEMM 128x384 (full-row) + exp + col-sums S + P16 in-place ---------
// grid 256, block 512 (8 waves, 2r x 4c; per-wave 64x96). In-place P16 safe: block owns its rows.
__global__ __launch_bounds__(512) void k_qps(
    const u16* __restrict__ xa16, const u16* __restrict__ WT, float* __restrict__ S,
    u16* __restrict__ P16)
{
  const int bm = blockIdx.x;            // 256 rowtiles of 128
  const int b = bm >> 5;
  const int n0 = bm << 7;
  const int tid = threadIdx.x;
  const int wv = tid >> 6, lane = tid & 63, l15 = lane & 15, quad = lane >> 4;
  const int wr = wv >> 2, wc = wv & 3;

  __shared__ __attribute__((aligned(16))) u16 lA[128][40];
  __shared__ __attribute__((aligned(16))) u16 lB[384][40];

  floatx4 acc[24];
  const floatx4 z = {0.f, 0.f, 0.f, 0.f};
#pragma unroll
  for (int i = 0; i < 24; i++) acc[i] = z;

  for (int k0 = 0; k0 < 384; k0 += 32) {
    __syncthreads();
    {                                                    // A: 128 x 32, 1 chunk/thread
      int r = tid >> 2, c8 = (tid & 3) << 3;
      *(u16x8*)&lA[r][c8] = *(const u16x8*)(xa16 + (size_t)(n0 + r) * 384 + k0 + c8);
    }
#pragma unroll
    for (int i = 0; i < 3; i++) {                        // B: 384 x 32
      int idx = tid + (i << 9);                          // 0..1535
      int cl = idx >> 2, ko = (idx & 3) << 3;
      *(u16x8*)&lB[cl][ko] = *(const u16x8*)(WT + (size_t)cl * 384 + k0 + ko);
    }
    __syncthreads();
    short8 af[4], bf[6];
#pragma unroll
    for (int mi = 0; mi < 4; mi++)
      af[mi] = *(const short8*)&lA[(wr << 6) + (mi << 4) + l15][quad << 3];
#pragma unroll
    for (int ni = 0; ni < 6; ni++)
      bf[ni] = *(const short8*)&lB[(wc * 96) + (ni << 4) + l15][quad << 3];
#pragma unroll
    for (int mi = 0; mi < 4; mi++)
#pragma unroll
      for (int ni = 0; ni < 6; ni++)
        acc[mi * 6 + ni] = __builtin_amdgcn_mfma_f32_16x16x32_bf16(af[mi], bf[ni], acc[mi * 6 + ni], 0, 0, 0);
  }

#pragma unroll
  for (int mi = 0; mi < 4; mi++)
#pragma unroll
    for (int ni = 0; ni < 6; ni++) {
      int col = wc * 96 + (ni << 4) + l15;
      int rowb = n0 + (wr << 6) + (mi << 4) + (quad << 2);
      float e0 = expf(acc[mi * 6 + ni][0]), e1 = expf(acc[mi * 6 + ni][1]);
      float e2 = expf(acc[mi * 6 + ni][2]), e3 = expf(acc[mi * 6 + ni][3]);
      P16[(size_t)(rowb + 0) * 384 + col] = f2bf(e0);
      P16[(size_t)(rowb + 1) * 384 + col] = f2bf(e1);
      P16[(size_t)(rowb + 2) * 384 + col] = f2bf(e2);
      P16[(size_t)(rowb + 3) * 384 + col] = f2bf(e3);
      float s = e0 + e1 + e2 + e3;
      s += __shfl_down(s, 32);
      s += __shfl_down(s, 16);
      if (lane < 16) atomicAdd(&S[b * 384 + wc * 96 + (ni << 4) + lane], s);
    }
}

// ---------------- Kernel 4: ctx[bh,48,48] += ksm^T @ v over 256-row n-chunks (MFMA) -------------
__global__ __launch_bounds__(256) void k_ctx(
    const u16* __restrict__ K16T, const u16* __restrict__ V16T, float* __restrict__ ctx)
{
  const int bh = blockIdx.x;           // 64
  const int b = bh >> 3, h = bh & 7;
  const int n0 = blockIdx.y << 8;      // chunk of 256 n
  const int tid = threadIdx.x;
  const int wv = tid >> 6, lane = tid & 63, l15 = lane & 15, quad = lane >> 4;

  __shared__ __attribute__((aligned(16))) char smem[50688];
  u16 (*lkT)[264] = (u16(*)[264])smem;             // 48 x 264 (ksm^T: [d][n])
  u16 (*lvT)[264] = (u16(*)[264])(smem + 25344);   // 48 x 264 (v^T:   [e][n])
  float (*pctx)[2304] = (float(*)[2304])smem;      // 4 x 2304 (overlaps, used after barrier)

#pragma unroll
  for (int i = 0; i < 6; i++) {
    int idx = tid + (i << 8);          // 0..1535
    int d = idx >> 5, c8 = (idx & 31) << 3;
    *(u16x8*)&lkT[d][c8] = *(const u16x8*)(K16T + ((size_t)b * 384 + h * 48 + d) * 4096 + n0 + c8);
    *(u16x8*)&lvT[d][c8] = *(const u16x8*)(V16T + ((size_t)b * 384 + h * 48 + d) * 4096 + n0 + c8);
  }
  __syncthreads();

  floatx4 c2[9];
  const floatx4 z = {0.f, 0.f, 0.f, 0.f};
#pragma unroll
  for (int i = 0; i < 9; i++) c2[i] = z;
#pragma unroll
  for (int kk2 = 0; kk2 < 2; kk2++) {
    int rb = (wv << 6) + (kk2 << 5) + (quad << 3);
    short8 ak[3], av[3];
#pragma unroll
    for (int t = 0; t < 3; t++) {
      ak[t] = *(const short8*)&lkT[(t << 4) + l15][rb];
      av[t] = *(const short8*)&lvT[(t << 4) + l15][rb];
    }
#pragma unroll
    for (int dt = 0; dt < 3; dt++)
#pragma unroll
      for (int et = 0; et < 3; et++)
        c2[dt * 3 + et] = __builtin_amdgcn_mfma_f32_16x16x32_bf16(ak[dt], av[et], c2[dt * 3 + et], 0, 0, 0);
  }
  __syncthreads();   // done reading lkT/lvT; smem reused as pctx

#pragma unroll
  for (int dt = 0; dt < 3; dt++)
#pragma unroll
    for (int et = 0; et < 3; et++)
#pragma unroll
      for (int rr = 0; rr < 4; rr++) {
        int d = (dt << 4) + (quad << 2) + rr;
        int e = (et << 4) + l15;
        pctx[wv][d * 48 + e] = c2[dt * 3 + et][rr];
      }
  __syncthreads();
#pragma unroll
  for (int i = 0; i < 9; i++) {
    int cell = tid + (i << 8);
    float s = pctx[0][cell] + pctx[1][cell] + pctx[2][cell] + pctx[3][cell];
    atomicAdd(&ctx[(size_t)bh * 2304 + cell], s);
  }
}

// ---------------- Kernel 5: W2T[b, c, h*48+d] = sum_e (ctx[bh,d,e]/S[..]) * wp[h*48+e, c] -------
__global__ __launch_bounds__(256) void k_w2(
    const float* __restrict__ ctx, const float* __restrict__ S,
    const float* __restrict__ wp, u16* __restrict__ W2T)
{
  const int bh = blockIdx.x;   // 64
  const int b = bh >> 3, h = bh & 7;
  const int c0 = blockIdx.y << 7;
  const int tid = threadIdx.x;
  __shared__ float rs[48];
  __shared__ float c2[48][48];
  __shared__ float lwp[48][128];
  __shared__ u16 tr[128][48];
  if (tid < 48) rs[tid] = 1.0f / S[b * 384 + h * 48 + tid];
  __syncthreads();
#pragma unroll
  for (int i = 0; i < 9; i++) {
    int cell = tid + (i << 8);
    int d = cell / 48, e = cell - d * 48;
    c2[d][e] = ctx[(size_t)bh * 2304 + cell] * rs[d];
  }
#pragma unroll
  for (int i = 0; i < 24; i++) {
    int idx = tid + (i << 8);            // 0..6143
    int e = idx >> 7, c = idx & 127;
    lwp[e][c] = wp[(size_t)(h * 48 + e) * 384 + c0 + c];
  }
  __syncthreads();
  const int c = tid & 127;
  const int dbase = tid >> 7;            // 0 or 1
#pragma unroll
  for (int it = 0; it < 24; it++) {
    int d = (it << 1) + dbase;
    float s = 0.f;
#pragma unroll
    for (int e = 0; e < 48; e++) s += c2[d][e] * lwp[e][c];
    tr[c][d] = f2bf(s);
  }
  __syncthreads();
  const int cc = tid >> 1, half = tid & 1;
#pragma unroll
  for (int i = 0; i < 3; i++) {
    u16x8 v = *(const u16x8*)&tr[cc][half * 24 + (i << 3)];
    *(u16x8*)(W2T + ((size_t)b * 384 + c0 + cc) * 384 + h * 48 + half * 24 + (i << 3)) = v;
  }
}

// ---------------- Kernel 6: out = P @ W2_b + bias + x, 128x384 full-row blocks ------------------
__global__ __launch_bounds__(512) void k_qproj(
    const u16* __restrict__ P16, const u16* __restrict__ W2T,
    const float* __restrict__ bias, const float* __restrict__ x, float* __restrict__ out)
{
  const int bm = blockIdx.x;            // 256 rowtiles of 128
  const int b = bm >> 5;
  const int n0 = bm << 7;
  const int tid = threadIdx.x;
  const int wv = tid >> 6, lane = tid & 63, l15 = lane & 15, quad = lane >> 4;
  const int wr = wv >> 2, wc = wv & 3;

  __shared__ __attribute__((aligned(16))) u16 lA[128][40];
  __shared__ __attribute__((aligned(16))) u16 lB[384][40];

  floatx4 acc[24];
  const floatx4 z = {0.f, 0.f, 0.f, 0.f};
#pragma unroll
  for (int i = 0; i < 24; i++) acc[i] = z;

  for (int k0 = 0; k0 < 384; k0 += 32) {
    __syncthreads();
    {
      int r = tid >> 2, c8 = (tid & 3) << 3;
      *(u16x8*)&lA[r][c8] = *(const u16x8*)(P16 + (size_t)(n0 + r) * 384 + k0 + c8);
    }
#pragma unroll
    for (int i = 0; i < 3; i++) {
      int idx = tid + (i << 9);
      int cl = idx >> 2, ko = (idx & 3) << 3;
      *(u16x8*)&lB[cl][ko] = *(const u16x8*)(W2T + ((size_t)b * 384 + cl) * 384 + k0 + ko);
    }
    __syncthreads();
    short8 af[4], bf[6];
#pragma unroll
    for (int mi = 0; mi < 4; mi++)
      af[mi] = *(const short8*)&lA[(wr << 6) + (mi << 4) + l15][quad << 3];
#pragma unroll
    for (int ni = 0; ni < 6; ni++)
      bf[ni] = *(const short8*)&lB[(wc * 96) + (ni << 4) + l15][quad << 3];
#pragma unroll
    for (int mi = 0; mi < 4; mi++)
#pragma unroll
      for (int ni = 0; ni < 6; ni++)
        acc[mi * 6 + ni] = __builtin_amdgcn_mfma_f32_16x16x32_bf16(af[mi], bf[ni], acc[mi * 6 + ni], 0, 0, 0);
  }

#pragma unroll
  for (int mi = 0; mi < 4; mi++)
#pragma unroll
    for (int ni = 0; ni < 6; ni++) {
      int col = wc * 96 + (ni << 4) + l15;
#pragma unroll
      for (int rr = 0; rr < 4; rr++) {
        int row = n0 + (wr << 6) + (mi << 4) + (quad << 2) + rr;
        float v = acc[mi * 6 + ni][rr] + bias[col] + x[(size_t)row * 384 + col];
        out[(size_t)row * 384 + col] = v;
      }
    }
}

extern "C" void kernel_launch(void* const* d_in, const int* in_sizes, int n_in,
                              void* d_out, int out_size, void* d_ws, size_t ws_size,
                              hipStream_t stream)
{
  const float* x      = (const float*)d_in[0];
  const float* w_sr   = (const float*)d_in[1];
  const float* b_sr   = (const float*)d_in[2];
  const float* ln_g   = (const float*)d_in[3];
  const float* ln_b   = (const float*)d_in[4];
  const float* w_qkv  = (const float*)d_in[5];
  const float* w_proj = (const float*)d_in[6];
  const float* b_proj = (const float*)d_in[7];
  float* out = (float*)d_out;

  // ws layout — total 29,011,968 bytes (~29 MB):
  //   [0,        12288)     S    [8][384] f32
  //   [12288,    602112)    ctx  [64][48][48] f32
  //   [602112,   1486848)   WT   [1152][384] bf16
  //   [1486848,  3846144)   W2T  [8][384][384] bf16
  //   [3846144,  29011968)  xa16 [32768][384] bf16  (overwritten in-place by P16=bf16(exp(q)))
  // d_out (50.3 MB) doubles as scratch for K16T+V16T (2 x 25.17 MB) until k_qproj writes it.
  float* S   = (float*)d_ws;
  float* ctx = (float*)((char*)d_ws + 12288);
  u16*   WT  = (u16*)((char*)d_ws + 602112);
  u16*   W2T = (u16*)((char*)d_ws + 1486848);
  u16*   xa16= (u16*)((char*)d_ws + 3846144);
  u16*   P16 = xa16;                     // in-place: k_qps overwrites its own rows after last read
  u16*   K16T= (u16*)d_out;              // [8][384][4096] bf16
  u16*   V16T= (u16*)d_out + (size_t)8 * 384 * 4096;

  hipMemsetAsync(d_ws, 0, 602112, stream);   // zero S + ctx

  k_prep<<<108, 256, 0, stream>>>(w_qkv, WT);
  k_conv_ln_gelu<<<BB * 512, 384, 0, stream>>>(x, w_sr, b_sr, ln_g, ln_b, xa16);
  k_kv<<<dim3(256, 4), 256, 0, stream>>>(xa16, WT, K16T, V16T);
  k_qps<<<256, 512, 0, stream>>>(xa16, WT, S, P16);
  k_ctx<<<dim3(64, 16), 256, 0, stream>>>(K16T, V16T, ctx);
  k_w2<<<dim3(64, 3), 256, 0, stream>>>(ctx, S, w_proj, W2T);
  k_qproj<<<256, 512, 0, stream>>>(P16, W2T, b_proj, x, out);
}

// Round 8
// 266.833 us; speedup vs baseline: 1.6037x; 1.1820x over previous
//
#include <hip/hip_runtime.h>

typedef unsigned short u16;
typedef u16   u16x4  __attribute__((ext_vector_type(4)));
typedef u16   u16x8  __attribute__((ext_vector_type(8)));
typedef short short8 __attribute__((ext_vector_type(8)));
typedef float floatx4 __attribute__((ext_vector_type(4)));
typedef float f4     __attribute__((ext_vector_type(4)));

#define BB 8
#define NN 4096
#define CC 384

__device__ __forceinline__ u16 f2bf(float f){
  unsigned u = __float_as_uint(f);
  u += 0x7FFFu + ((u >> 16) & 1u);   // round-to-nearest-even
  return (u16)(u >> 16);
}

// ---------------- Kernel 0: WT[col][k] = bf16(wqkv[k][col])  (1152 x 384, one-time transpose) ----
__global__ __launch_bounds__(256) void k_prep(const float* __restrict__ wqkv, u16* __restrict__ WT)
{
  const int cg = blockIdx.x % 18;        // 18 col-groups of 64
  const int kg = blockIdx.x / 18;        // 6 k-groups of 64
  const int c0 = cg << 6, k0 = kg << 6;
  const int tid = threadIdx.x;
  __shared__ u16 t[64][72];
#pragma unroll
  for (int i = 0; i < 4; i++) {
    int idx = tid + (i << 8);            // 0..1023
    int r = idx >> 4, c4 = (idx & 15) << 2;
    f4 v = *(const f4*)(wqkv + (size_t)(k0 + r) * 1152 + c0 + c4);
#pragma unroll
    for (int j = 0; j < 4; j++) t[c4 + j][r] = f2bf(v[j]);
  }
  __syncthreads();
#pragma unroll
  for (int i = 0; i < 2; i++) {
    int idx = tid + (i << 8);            // 0..511
    int c = idx >> 3, j = (idx & 7) << 3;
    *(u16x8*)(WT + (size_t)(c0 + c) * 384 + k0 + j) = *(const u16x8*)&t[c][j];
  }
}

// ---------------- Kernel 1: depthwise conv 3x3 + LN + GELU(erf) + residual -> xa16 (bf16) -------
__global__ __launch_bounds__(384) void k_conv_ln_gelu(
    const float* __restrict__ x, const float* __restrict__ w_sr, const float* __restrict__ b_sr,
    const float* __restrict__ ln_g, const float* __restrict__ ln_b, u16* __restrict__ xa16)
{
  const int blk = blockIdx.x;          // b*512 + hh*8 + wg
  const int b = blk >> 9;
  const int hh = (blk >> 3) & 63;
  const int ww0 = (blk & 7) << 3;      // pixels ww0..ww0+7
  const int c = threadIdx.x;

  float wgt[9];
#pragma unroll
  for (int i = 0; i < 9; i++) wgt[i] = w_sr[c * 9 + i];
  const float lg = ln_g[c], lb = ln_b[c];
  const float bias = b_sr[c];

  float rowv[3][10];
#pragma unroll
  for (int r = 0; r < 3; r++) {
    int y = hh + r - 1;
    bool yok = (unsigned)y < 64u;
#pragma unroll
    for (int j = 0; j < 10; j++) {
      int xx = ww0 + j - 1;
      bool ok = yok && ((unsigned)xx < 64u);
      rowv[r][j] = ok ? x[((size_t)((b << 12) + (y << 6) + xx)) * CC + c] : 0.f;
    }
  }

  float acc[8];
#pragma unroll
  for (int p = 0; p < 8; p++) {
    float a = bias;
#pragma unroll
    for (int r = 0; r < 3; r++)
#pragma unroll
      for (int j = 0; j < 3; j++)
        a += rowv[r][p + j] * wgt[r * 3 + j];
    acc[p] = a;
  }

  __shared__ float ls1[6][8], ls2[6][8], mb[2][8];
  const int wid = threadIdx.x >> 6, lane = threadIdx.x & 63;
#pragma unroll
  for (int p = 0; p < 8; p++) {
    float s1 = acc[p], s2 = acc[p] * acc[p];
#pragma unroll
    for (int o = 32; o > 0; o >>= 1) { s1 += __shfl_down(s1, o); s2 += __shfl_down(s2, o); }
    if (lane == 0) { ls1[wid][p] = s1; ls2[wid][p] = s2; }
  }
  __syncthreads();
  if (threadIdx.x < 8) {
    int p = threadIdx.x;
    float a = 0.f, q = 0.f;
#pragma unroll
    for (int i = 0; i < 6; i++) { a += ls1[i][p]; q += ls2[i][p]; }
    float mean = a * (1.0f / CC);
    float var  = q * (1.0f / CC) - mean * mean;
    mb[0][p] = mean; mb[1][p] = rsqrtf(var + 1e-5f);
  }
  __syncthreads();
#pragma unroll
  for (int p = 0; p < 8; p++) {
    float xn = (acc[p] - mb[0][p]) * mb[1][p] * lg + lb;
    float g  = 0.5f * xn * (1.0f + erff(xn * 0.70710678118654752f));
    size_t pix = (size_t)(b << 12) + (hh << 6) + ww0 + p;
    xa16[pix * CC + c] = f2bf(rowv[1][p + 1] + g);   // center tap doubles as residual
  }
}

// ================= Shared GEMM template: 64 rows x 384 cols, 512 thr, 8 waves x (64x48) =========
// Single LDS buffer + register prefetch: loads for k-step t+1 issued BEFORE compute of t,
// LDS-written AFTER it (latency hidden under ds_read+MFMA). 12 acc f4 per wave (low VGPR).

// ---------------- Kernel 2: k|v GEMM + per-head register softmax -> K16T/V16T (transposed) ------
__global__ __launch_bounds__(512) void k_kv(
    const u16* __restrict__ xa16, const u16* __restrict__ WT,
    u16* __restrict__ K16T, u16* __restrict__ V16T)
{
  const int rt = blockIdx.x;            // 512 rowtiles of 64
  const int g  = blockIdx.y;            // 0=k, 1=v
  const int b  = rt >> 6;
  const int n0 = rt << 6;
  const int tid = threadIdx.x;
  const int wv = tid >> 6, lane = tid & 63, l15 = lane & 15, quad = lane >> 4;
  const int wc = wv;                    // wave = head (48 cols)

  __shared__ __attribute__((aligned(16))) u16 lA[64][40];
  __shared__ __attribute__((aligned(16))) u16 lB[384][40];

  const u16* Bbase = WT + (size_t)(384 + g * 384) * 384;
  const int rA = tid >> 2, cA = (tid & 3) << 3;   // A-staging slot (tid<256 only)

  floatx4 acc[12];
  const floatx4 z = {0.f, 0.f, 0.f, 0.f};
#pragma unroll
  for (int i = 0; i < 12; i++) acc[i] = z;

  // prologue: stage k0=0
  if (tid < 256)
    *(u16x8*)&lA[rA][cA] = *(const u16x8*)(xa16 + (size_t)(n0 + rA) * 384 + cA);
#pragma unroll
  for (int i = 0; i < 3; i++) {
    int idx = tid + (i << 9);
    *(u16x8*)&lB[idx >> 2][(idx & 3) << 3] = *(const u16x8*)(Bbase + (size_t)(idx >> 2) * 384 + ((idx & 3) << 3));
  }
  __syncthreads();

  for (int t = 0; t < 12; t++) {
    u16x8 ra, rb[3];
    const bool pf = (t < 11);
    const int kn = (t + 1) << 5;
    if (pf) {
      if (tid < 256) ra = *(const u16x8*)(xa16 + (size_t)(n0 + rA) * 384 + kn + cA);
#pragma unroll
      for (int i = 0; i < 3; i++) {
        int idx = tid + (i << 9);
        rb[i] = *(const u16x8*)(Bbase + (size_t)(idx >> 2) * 384 + kn + ((idx & 3) << 3));
      }
    }
    short8 af[4], bf[3];
#pragma unroll
    for (int mi = 0; mi < 4; mi++) af[mi] = *(const short8*)&lA[(mi << 4) + l15][quad << 3];
#pragma unroll
    for (int ni = 0; ni < 3; ni++) bf[ni] = *(const short8*)&lB[wc * 48 + (ni << 4) + l15][quad << 3];
#pragma unroll
    for (int mi = 0; mi < 4; mi++)
#pragma unroll
      for (int ni = 0; ni < 3; ni++)
        acc[mi * 3 + ni] = __builtin_amdgcn_mfma_f32_16x16x32_bf16(af[mi], bf[ni], acc[mi * 3 + ni], 0, 0, 0);
    __syncthreads();
    if (pf) {
      if (tid < 256) *(u16x8*)&lA[rA][cA] = ra;
#pragma unroll
      for (int i = 0; i < 3; i++) {
        int idx = tid + (i << 9);
        *(u16x8*)&lB[idx >> 2][(idx & 3) << 3] = rb[i];
      }
    }
    __syncthreads();
  }

  if (g == 0) {
    // per-row softmax over this wave's head (48 cols = 3 regs x 16 l15 lanes)
#pragma unroll
    for (int mi = 0; mi < 4; mi++)
#pragma unroll
      for (int rr = 0; rr < 4; rr++) {
        float x0 = acc[mi * 3 + 0][rr], x1 = acc[mi * 3 + 1][rr], x2 = acc[mi * 3 + 2][rr];
        float m = fmaxf(fmaxf(x0, x1), x2);
#pragma unroll
        for (int o = 8; o >= 1; o >>= 1) m = fmaxf(m, __shfl_xor(m, o));
        float e0 = expf(x0 - m), e1 = expf(x1 - m), e2 = expf(x2 - m);
        float s = e0 + e1 + e2;
#pragma unroll
        for (int o = 8; o >= 1; o >>= 1) s += __shfl_xor(s, o);
        float inv = 1.0f / s;
        acc[mi * 3 + 0][rr] = e0 * inv; acc[mi * 3 + 1][rr] = e1 * inv; acc[mi * 3 + 2][rr] = e2 * inv;
      }
  }

  u16* dst = g ? V16T : K16T;
  const int nl = ((rt & 63) << 6) + (quad << 2);
#pragma unroll
  for (int mi = 0; mi < 4; mi++)
#pragma unroll
    for (int ni = 0; ni < 3; ni++) {
      int hd = wc * 48 + (ni << 4) + l15;
      u16x4 v4 = { f2bf(acc[mi * 3 + ni][0]), f2bf(acc[mi * 3 + ni][1]),
                   f2bf(acc[mi * 3 + ni][2]), f2bf(acc[mi * 3 + ni][3]) };
      *(u16x4*)(dst + ((size_t)b * 384 + hd) * 4096 + nl + (mi << 4)) = v4;
    }
}

// ---------------- Kernel 3: q GEMM + exp + col-sums S + P16 in-place ----------------------------
__global__ __launch_bounds__(512) void k_qps(
    const u16* __restrict__ xa16, const u16* __restrict__ WT, float* __restrict__ S,
    u16* __restrict__ P16)
{
  const int bm = blockIdx.x;            // 512 rowtiles of 64
  const int b = bm >> 6;
  const int n0 = bm << 6;
  const int tid = threadIdx.x;
  const int wv = tid >> 6, lane = tid & 63, l15 = lane & 15, quad = lane >> 4;
  const int wc = wv;

  __shared__ __attribute__((aligned(16))) u16 lA[64][40];
  __shared__ __attribute__((aligned(16))) u16 lB[384][40];

  const u16* Bbase = WT;                 // q group = WT rows 0..383
  const int rA = tid >> 2, cA = (tid & 3) << 3;

  floatx4 acc[12];
  const floatx4 z = {0.f, 0.f, 0.f, 0.f};
#pragma unroll
  for (int i = 0; i < 12; i++) acc[i] = z;

  if (tid < 256)
    *(u16x8*)&lA[rA][cA] = *(const u16x8*)(xa16 + (size_t)(n0 + rA) * 384 + cA);
#pragma unroll
  for (int i = 0; i < 3; i++) {
    int idx = tid + (i << 9);
    *(u16x8*)&lB[idx >> 2][(idx & 3) << 3] = *(const u16x8*)(Bbase + (size_t)(idx >> 2) * 384 + ((idx & 3) << 3));
  }
  __syncthreads();

  for (int t = 0; t < 12; t++) {
    u16x8 ra, rb[3];
    const bool pf = (t < 11);
    const int kn = (t + 1) << 5;
    if (pf) {
      if (tid < 256) ra = *(const u16x8*)(xa16 + (size_t)(n0 + rA) * 384 + kn + cA);
#pragma unroll
      for (int i = 0; i < 3; i++) {
        int idx = tid + (i << 9);
        rb[i] = *(const u16x8*)(Bbase + (size_t)(idx >> 2) * 384 + kn + ((idx & 3) << 3));
      }
    }
    short8 af[4], bf[3];
#pragma unroll
    for (int mi = 0; mi < 4; mi++) af[mi] = *(const short8*)&lA[(mi << 4) + l15][quad << 3];
#pragma unroll
    for (int ni = 0; ni < 3; ni++) bf[ni] = *(const short8*)&lB[wc * 48 + (ni << 4) + l15][quad << 3];
#pragma unroll
    for (int mi = 0; mi < 4; mi++)
#pragma unroll
      for (int ni = 0; ni < 3; ni++)
        acc[mi * 3 + ni] = __builtin_amdgcn_mfma_f32_16x16x32_bf16(af[mi], bf[ni], acc[mi * 3 + ni], 0, 0, 0);
    __syncthreads();
    if (pf) {
      if (tid < 256) *(u16x8*)&lA[rA][cA] = ra;
#pragma unroll
      for (int i = 0; i < 3; i++) {
        int idx = tid + (i << 9);
        *(u16x8*)&lB[idx >> 2][(idx & 3) << 3] = rb[i];
      }
    }
    __syncthreads();
  }

#pragma unroll
  for (int ni = 0; ni < 3; ni++) {
    int col = wc * 48 + (ni << 4) + l15;
    float s = 0.f;
#pragma unroll
    for (int mi = 0; mi < 4; mi++) {
      int rowb = n0 + (mi << 4) + (quad << 2);
      float e0 = expf(acc[mi * 3 + ni][0]), e1 = expf(acc[mi * 3 + ni][1]);
      float e2 = expf(acc[mi * 3 + ni][2]), e3 = expf(acc[mi * 3 + ni][3]);
      P16[(size_t)(rowb + 0) * 384 + col] = f2bf(e0);
      P16[(size_t)(rowb + 1) * 384 + col] = f2bf(e1);
      P16[(size_t)(rowb + 2) * 384 + col] = f2bf(e2);
      P16[(size_t)(rowb + 3) * 384 + col] = f2bf(e3);
      s += e0 + e1 + e2 + e3;
    }
    s += __shfl_down(s, 32);
    s += __shfl_down(s, 16);
    if (lane < 16) atomicAdd(&S[b * 384 + wc * 48 + (ni << 4) + lane], s);
  }
}

// ---------------- Kernel 4: ctx[bh,48,48] += ksm^T @ v over 256-row n-chunks (MFMA) -------------
__global__ __launch_bounds__(256) void k_ctx(
    const u16* __restrict__ K16T, const u16* __restrict__ V16T, float* __restrict__ ctx)
{
  const int bh = blockIdx.x;           // 64
  const int b = bh >> 3, h = bh & 7;
  const int n0 = blockIdx.y << 8;      // chunk of 256 n
  const int tid = threadIdx.x;
  const int wv = tid >> 6, lane = tid & 63, l15 = lane & 15, quad = lane >> 4;

  __shared__ __attribute__((aligned(16))) char smem[50688];
  u16 (*lkT)[264] = (u16(*)[264])smem;             // 48 x 264 (ksm^T: [d][n])
  u16 (*lvT)[264] = (u16(*)[264])(smem + 25344);   // 48 x 264 (v^T:   [e][n])
  float (*pctx)[2304] = (float(*)[2304])smem;      // 4 x 2304 (overlaps, used after barrier)

#pragma unroll
  for (int i = 0; i < 6; i++) {
    int idx = tid + (i << 8);          // 0..1535
    int d = idx >> 5, c8 = (idx & 31) << 3;
    *(u16x8*)&lkT[d][c8] = *(const u16x8*)(K16T + ((size_t)b * 384 + h * 48 + d) * 4096 + n0 + c8);
    *(u16x8*)&lvT[d][c8] = *(const u16x8*)(V16T + ((size_t)b * 384 + h * 48 + d) * 4096 + n0 + c8);
  }
  __syncthreads();

  floatx4 c2[9];
  const floatx4 z = {0.f, 0.f, 0.f, 0.f};
#pragma unroll
  for (int i = 0; i < 9; i++) c2[i] = z;
#pragma unroll
  for (int kk2 = 0; kk2 < 2; kk2++) {
    int rb = (wv << 6) + (kk2 << 5) + (quad << 3);
    short8 ak[3], av[3];
#pragma unroll
    for (int t = 0; t < 3; t++) {
      ak[t] = *(const short8*)&lkT[(t << 4) + l15][rb];
      av[t] = *(const short8*)&lvT[(t << 4) + l15][rb];
    }
#pragma unroll
    for (int dt = 0; dt < 3; dt++)
#pragma unroll
      for (int et = 0; et < 3; et++)
        c2[dt * 3 + et] = __builtin_amdgcn_mfma_f32_16x16x32_bf16(ak[dt], av[et], c2[dt * 3 + et], 0, 0, 0);
  }
  __syncthreads();   // done reading lkT/lvT; smem reused as pctx

#pragma unroll
  for (int dt = 0; dt < 3; dt++)
#pragma unroll
    for (int et = 0; et < 3; et++)
#pragma unroll
      for (int rr = 0; rr < 4; rr++) {
        int d = (dt << 4) + (quad << 2) + rr;
        int e = (et << 4) + l15;
        pctx[wv][d * 48 + e] = c2[dt * 3 + et][rr];
      }
  __syncthreads();
#pragma unroll
  for (int i = 0; i < 9; i++) {
    int cell = tid + (i << 8);
    float s = pctx[0][cell] + pctx[1][cell] + pctx[2][cell] + pctx[3][cell];
    atomicAdd(&ctx[(size_t)bh * 2304 + cell], s);
  }
}

// ---------------- Kernel 5: W2T[b, c, h*48+d] = sum_e (ctx[bh,d,e]/S[..]) * wp[h*48+e, c] -------
__global__ __launch_bounds__(256) void k_w2(
    const float* __restrict__ ctx, const float* __restrict__ S,
    const float* __restrict__ wp, u16* __restrict__ W2T)
{
  const int bh = blockIdx.x;   // 64
  const int b = bh >> 3, h = bh & 7;
  const int c0 = blockIdx.y << 7;
  const int tid = threadIdx.x;
  __shared__ float rs[48];
  __shared__ float c2[48][48];
  __shared__ float lwp[48][128];
  __shared__ u16 tr[128][48];
  if (tid < 48) rs[tid] = 1.0f / S[b * 384 + h * 48 + tid];
  __syncthreads();
#pragma unroll
  for (int i = 0; i < 9; i++) {
    int cell = tid + (i << 8);
    int d = cell / 48, e = cell - d * 48;
    c2[d][e] = ctx[(size_t)bh * 2304 + cell] * rs[d];
  }
#pragma unroll
  for (int i = 0; i < 24; i++) {
    int idx = tid + (i << 8);            // 0..6143
    int e = idx >> 7, c = idx & 127;
    lwp[e][c] = wp[(size_t)(h * 48 + e) * 384 + c0 + c];
  }
  __syncthreads();
  const int c = tid & 127;
  const int dbase = tid >> 7;            // 0 or 1
#pragma unroll
  for (int it = 0; it < 24; it++) {
    int d = (it << 1) + dbase;
    float s = 0.f;
#pragma unroll
    for (int e = 0; e < 48; e++) s += c2[d][e] * lwp[e][c];
    tr[c][d] = f2bf(s);
  }
  __syncthreads();
  const int cc = tid >> 1, half = tid & 1;
#pragma unroll
  for (int i = 0; i < 3; i++) {
    u16x8 v = *(const u16x8*)&tr[cc][half * 24 + (i << 3)];
    *(u16x8*)(W2T + ((size_t)b * 384 + c0 + cc) * 384 + h * 48 + half * 24 + (i << 3)) = v;
  }
}

// ---------------- Kernel 6: out = P @ W2_b + bias + x  (same pipelined template) ----------------
__global__ __launch_bounds__(512) void k_qproj(
    const u16* __restrict__ P16, const u16* __restrict__ W2T,
    const float* __restrict__ bias, const float* __restrict__ x, float* __restrict__ out)
{
  const int bm = blockIdx.x;            // 512 rowtiles of 64
  const int b = bm >> 6;
  const int n0 = bm << 6;
  const int tid = threadIdx.x;
  const int wv = tid >> 6, lane = tid & 63, l15 = lane & 15, quad = lane >> 4;
  const int wc = wv;

  __shared__ __attribute__((aligned(16))) u16 lA[64][40];
  __shared__ __attribute__((aligned(16))) u16 lB[384][40];

  const u16* Bbase = W2T + (size_t)b * 384 * 384;
  const int rA = tid >> 2, cA = (tid & 3) << 3;

  floatx4 acc[12];
  const floatx4 z = {0.f, 0.f, 0.f, 0.f};
#pragma unroll
  for (int i = 0; i < 12; i++) acc[i] = z;

  if (tid < 256)
    *(u16x8*)&lA[rA][cA] = *(const u16x8*)(P16 + (size_t)(n0 + rA) * 384 + cA);
#pragma unroll
  for (int i = 0; i < 3; i++) {
    int idx = tid + (i << 9);
    *(u16x8*)&lB[idx >> 2][(idx & 3) << 3] = *(const u16x8*)(Bbase + (size_t)(idx >> 2) * 384 + ((idx & 3) << 3));
  }
  __syncthreads();

  for (int t = 0; t < 12; t++) {
    u16x8 ra, rb[3];
    const bool pf = (t < 11);
    const int kn = (t + 1) << 5;
    if (pf) {
      if (tid < 256) ra = *(const u16x8*)(P16 + (size_t)(n0 + rA) * 384 + kn + cA);
#pragma unroll
      for (int i = 0; i < 3; i++) {
        int idx = tid + (i << 9);
        rb[i] = *(const u16x8*)(Bbase + (size_t)(idx >> 2) * 384 + kn + ((idx & 3) << 3));
      }
    }
    short8 af[4], bf[3];
#pragma unroll
    for (int mi = 0; mi < 4; mi++) af[mi] = *(const short8*)&lA[(mi << 4) + l15][quad << 3];
#pragma unroll
    for (int ni = 0; ni < 3; ni++) bf[ni] = *(const short8*)&lB[wc * 48 + (ni << 4) + l15][quad << 3];
#pragma unroll
    for (int mi = 0; mi < 4; mi++)
#pragma unroll
      for (int ni = 0; ni < 3; ni++)
        acc[mi * 3 + ni] = __builtin_amdgcn_mfma_f32_16x16x32_bf16(af[mi], bf[ni], acc[mi * 3 + ni], 0, 0, 0);
    __syncthreads();
    if (pf) {
      if (tid < 256) *(u16x8*)&lA[rA][cA] = ra;
#pragma unroll
      for (int i = 0; i < 3; i++) {
        int idx = tid + (i << 9);
        *(u16x8*)&lB[idx >> 2][(idx & 3) << 3] = rb[i];
      }
    }
    __syncthreads();
  }

#pragma unroll
  for (int ni = 0; ni < 3; ni++) {
    int col = wc * 48 + (ni << 4) + l15;
    float bc = bias[col];
#pragma unroll
    for (int mi = 0; mi < 4; mi++) {
#pragma unroll
      for (int rr = 0; rr < 4; rr++) {
        int row = n0 + (mi << 4) + (quad << 2) + rr;
        out[(size_t)row * 384 + col] = acc[mi * 3 + ni][rr] + bc + x[(size_t)row * 384 + col];
      }
    }
  }
}

extern "C" void kernel_launch(void* const* d_in, const int* in_sizes, int n_in,
                              void* d_out, int out_size, void* d_ws, size_t ws_size,
                              hipStream_t stream)
{
  const float* x      = (const float*)d_in[0];
  const float* w_sr   = (const float*)d_in[1];
  const float* b_sr   = (const float*)d_in[2];
  const float* ln_g   = (const float*)d_in[3];
  const float* ln_b   = (const float*)d_in[4];
  const float* w_qkv  = (const float*)d_in[5];
  const float* w_proj = (const float*)d_in[6];
  const float* b_proj = (const float*)d_in[7];
  float* out = (float*)d_out;

  // ws layout — total 29,011,968 bytes (~29 MB):
  //   [0,        12288)     S    [8][384] f32
  //   [12288,    602112)    ctx  [64][48][48] f32
  //   [602112,   1486848)   WT   [1152][384] bf16
  //   [1486848,  3846144)   W2T  [8][384][384] bf16
  //   [3846144,  29011968)  xa16 [32768][384] bf16  (overwritten in-place by P16=bf16(exp(q)))
  // d_out (50.3 MB) doubles as scratch for K16T+V16T (2 x 25.17 MB) until k_qproj writes it.
  float* S   = (float*)d_ws;
  float* ctx = (float*)((char*)d_ws + 12288);
  u16*   WT  = (u16*)((char*)d_ws + 602112);
  u16*   W2T = (u16*)((char*)d_ws + 1486848);
  u16*   xa16= (u16*)((char*)d_ws + 3846144);
  u16*   P16 = xa16;                     // in-place: k_qps overwrites its own rows after last read
  u16*   K16T= (u16*)d_out;              // [8][384][4096] bf16
  u16*   V16T= (u16*)d_out + (size_t)8 * 384 * 4096;

  hipMemsetAsync(d_ws, 0, 602112, stream);   // zero S + ctx

  k_prep<<<108, 256, 0, stream>>>(w_qkv, WT);
  k_conv_ln_gelu<<<BB * 512, 384, 0, stream>>>(x, w_sr, b_sr, ln_g, ln_b, xa16);
  k_kv<<<dim3(512, 2), 512, 0, stream>>>(xa16, WT, K16T, V16T);
  k_qps<<<512, 512, 0, stream>>>(xa16, WT, S, P16);
  k_ctx<<<dim3(64, 16), 256, 0, stream>>>(K16T, V16T, ctx);
  k_w2<<<dim3(64, 3), 256, 0, stream>>>(ctx, S, w_proj, W2T);
  k_qproj<<<512, 512, 0, stream>>>(P16, W2T, b_proj, x, out);
}